// Round 5
// baseline (8925.094 us; speedup 1.0000x reference)
//
#include <hip/hip_runtime.h>

// Problem constants
#define NB 512   // batch
#define NT 512   // time
#define NI 128   // input dim
#define NH 256   // hidden dim
#define NG 1024  // 4*NH gate rows
#define NKT 12   // K tiles of 32 (K = 384 = [x(128) | h(256)])
#define GS 16    // sequences per group (= MFMA N)
#define NGRP 32  // groups
#define NSL 8    // slices (blocks) per group
#define EPSV 1e-5f

typedef __attribute__((ext_vector_type(8))) short bf16x8;
typedef __attribute__((ext_vector_type(4))) float f32x4;

__device__ __forceinline__ unsigned short f32_to_bf16(float f) {
  unsigned int u = __float_as_uint(f);
  u += 0x7fffu + ((u >> 16) & 1u);   // RNE
  return (unsigned short)(u >> 16);
}
__device__ __forceinline__ float sigm(float x) { return 1.f / (1.f + __expf(-x)); }
__device__ __forceinline__ float tanhv(float x) { return 1.f - 2.f / (1.f + __expf(2.f * x)); }

// ---------------------------------------------------------------------------
// Prep: swizzle weights into per-slice A-fragment order + zero group counters.
// Linear idx = (((m*8 + rt)*12 + kt)*64 + lane)*8 + i
//   slice m, row-tile rt = 2*wave + p, k-tile kt, lane, elem i.
//   A-frag: tile-row rr = lane&15, k = kt*32 + (lane>>4)*8 + i.
//   Tile row composition: p=0 -> rows 0-7 = gate i, 8-15 = gate f of units
//   u = rr&7;  p=1 -> gates g / o.  Unit j = 32m + 8*wave + (rr&7).
// ---------------------------------------------------------------------------
__global__ void prep_kernel(const float* __restrict__ W_ih, const float* __restrict__ W_hh,
                            const float* __restrict__ b_ih, const float* __restrict__ b_hh,
                            unsigned short* __restrict__ Wsw, float* __restrict__ bsum,
                            int* __restrict__ cnt) {
  int idx = blockIdx.x * blockDim.x + threadIdx.x;   // 64*12*512 = 393216
  if (idx < 64 * NKT * 512) {
    int i    = idx & 7;
    int lane = (idx >> 3) & 63;
    int kt   = (idx >> 9) % NKT;
    int rtg  = (idx >> 9) / NKT;      // 0..63
    int m    = rtg >> 3;
    int rt   = rtg & 7;
    int wv   = rt >> 1;
    int p    = rt & 1;
    int rr   = lane & 15;
    int k    = kt * 32 + (lane >> 4) * 8 + i;
    int q    = p * 2 + (rr >> 3);
    int j    = 32 * m + 8 * wv + (rr & 7);
    int gr   = q * NH + j;
    float w = (k < NI) ? W_ih[gr * NI + k] : W_hh[gr * NH + (k - NI)];
    Wsw[idx] = f32_to_bf16(w);
  }
  if (idx < NG) bsum[idx] = b_ih[idx] + b_hh[idx];
  if (idx < NGRP) cnt[idx] = 0;
}

// ---------------------------------------------------------------------------
// Rank-sort by length (descending) -> perm
// ---------------------------------------------------------------------------
__global__ void sort_kernel(const int* __restrict__ lengths, int* __restrict__ perm) {
  int i = threadIdx.x;
  __shared__ int L[NB];
  int li = lengths[i];
  L[i] = li;
  __syncthreads();
  int r = 0;
  for (int k = 0; k < NB; ++k) {
    int lk = L[k];
    r += (lk > li) || (lk == li && k < i);
  }
  perm[r] = i;
}

// ---------------------------------------------------------------------------
// Main: 256 blocks x 256 threads, 1 block/CU. Group g = 8 blocks (slices),
// slice m owns units [32m, 32m+32): 128 gate rows = 24 A-frags held in VGPRs
// for the whole kernel. Per step: 12 ds_read_b128 (B) + 24 MFMA + cell, then
// the 8 slices exchange 1 KB h-chunks via agent-scope atomics (double-buffered
// Hbuf + monotonic counter barrier).
// ---------------------------------------------------------------------------
__global__ __launch_bounds__(256, 1)
void lstm_ln_kernel(const float* __restrict__ X, const int* __restrict__ lengths,
                    const int* __restrict__ perm, const unsigned short* __restrict__ Wsw,
                    const float* __restrict__ bsum, const float* __restrict__ gamma,
                    const float* __restrict__ beta, float* __restrict__ out,
                    unsigned int* __restrict__ HbufU, unsigned int* __restrict__ HfinU,
                    int* __restrict__ cnt) {
  __shared__ alignas(16) unsigned short xh[NKT * 512];  // 12 KB, B-frag order
  __shared__ alignas(16) unsigned short hstage[512];    // own h chunk [ul*16+c]
  __shared__ alignas(16) float hf[512];                 // final h f32 [ul*16+c]
  __shared__ float red[20];
  __shared__ int sseq[GS], slen[GS];

  const int g = blockIdx.x >> 3;
  const int m = blockIdx.x & 7;
  const int tid = threadIdx.x;
  const int w = tid >> 6;
  const int lane = tid & 63;
  const int quad = lane >> 4;
  const int col = lane & 15;

  if (tid < GS) {
    int s = perm[g * GS + tid];
    sseq[tid] = s;
    slen[tid] = lengths[s];
  }
  for (int v = tid; v < NKT * 512; v += 256) xh[v] = 0;   // h(=k 128..383) starts 0
  __syncthreads();
  const int lmax = slen[0];
  const int lenc = slen[col];

  // ---- 24 A-frags -> registers (persistent) ----
  const bf16x8* __restrict__ Wf = (const bf16x8*)Wsw;
  bf16x8 A0[NKT], A1[NKT];
  {
    const int base0 = ((m * 8 + 2 * w + 0) * NKT) * 64 + lane;
    const int base1 = ((m * 8 + 2 * w + 1) * NKT) * 64 + lane;
#pragma unroll
    for (int kt = 0; kt < NKT; ++kt) {
      A0[kt] = Wf[base0 + kt * 64];
      A1[kt] = Wf[base1 + kt * 64];
    }
  }

  // ---- bias fragments (D row = quad*4 + r) ----
  f32x4 bias0, bias1;
#pragma unroll
  for (int r = 0; r < 4; ++r) {
    int row = quad * 4 + r;
    int hi = row >> 3;
    int j = 32 * m + 8 * w + (row & 7);
    bias0[r] = bsum[(0 + hi) * NH + j];
    bias1[r] = bsum[(2 + hi) * NH + j];
  }

  // ---- x staging mapping: thread -> (seq xb, k-octet xk0) ----
  const int xb = tid >> 4, xk0 = (tid & 15) * 8;
  const float* __restrict__ xptr = X + (size_t)sseq[xb] * NT * NI + xk0;
  const int xdst = (xk0 >> 5) * 512 + (((xk0 & 31) >> 3) * 16 + xb) * 8;
  float4 xpa, xpb;
  {  // stage x(0)
    float4 a = *(const float4*)xptr;
    float4 b = *(const float4*)(xptr + 4);
    bf16x8 xv;
    xv[0] = (short)f32_to_bf16(a.x); xv[1] = (short)f32_to_bf16(a.y);
    xv[2] = (short)f32_to_bf16(a.z); xv[3] = (short)f32_to_bf16(a.w);
    xv[4] = (short)f32_to_bf16(b.x); xv[5] = (short)f32_to_bf16(b.y);
    xv[6] = (short)f32_to_bf16(b.z); xv[7] = (short)f32_to_bf16(b.w);
    *(bf16x8*)&xh[xdst] = xv;
  }
  if (lmax > 1) {   // prefetch x(1)
    xpa = *(const float4*)(xptr + NI);
    xpb = *(const float4*)(xptr + NI + 4);
  }
  __syncthreads();

  float c[4] = {0.f, 0.f, 0.f, 0.f}, h[4] = {0.f, 0.f, 0.f, 0.f};

  for (int t = 0; t < lmax; ++t) {
    // ---- GEMM slice: 24 MFMA on register A, LDS B ----
    f32x4 acc0 = bias0, acc1 = bias1;
#pragma unroll
    for (int kt = 0; kt < NKT; ++kt) {
      bf16x8 bf = *(const bf16x8*)&xh[kt * 512 + lane * 8];
      acc0 = __builtin_amdgcn_mfma_f32_16x16x32_bf16(A0[kt], bf, acc0, 0, 0, 0);
      acc1 = __builtin_amdgcn_mfma_f32_16x16x32_bf16(A1[kt], bf, acc1, 0, 0, 0);
    }

    // ---- cell update: lanes<32 hold i/g rows; f/o live at lane^32 ----
    float fp[4], op[4];
#pragma unroll
    for (int r = 0; r < 4; ++r) {
      fp[r] = __shfl_xor(acc0[r], 32);
      op[r] = __shfl_xor(acc1[r], 32);
    }
    if (lane < 32) {
      const bool upd = (t < lenc);
#pragma unroll
      for (int r = 0; r < 4; ++r) {
        float ig = sigm(acc0[r]);
        float gg = tanhv(acc1[r]);
        float fg = sigm(fp[r]);
        float og = sigm(op[r]);
        float cn = fg * c[r] + ig * gg;
        float hn = og * tanhv(cn);
        if (upd) { c[r] = cn; h[r] = hn; }
        int ul = 8 * w + 4 * quad + r;            // local unit 0..31
        hstage[ul * 16 + col] = f32_to_bf16(h[r]); // frozen value if !upd
      }
    }
    __syncthreads();   // hstage ready; all B-frag reads done

    // ---- publish own chunk (256 uints, coalesced, agent-coherent) ----
    {
      unsigned int vv = ((const unsigned int*)hstage)[tid];
      __hip_atomic_store(&HbufU[((size_t)(t & 1) * NGRP + g) * 2048 + m * 256 + tid], vv,
                         __ATOMIC_RELAXED, __HIP_MEMORY_SCOPE_AGENT);
    }
    __threadfence();
    __syncthreads();
    if (tid == 0) {
      __hip_atomic_fetch_add(&cnt[g], 1, __ATOMIC_RELEASE, __HIP_MEMORY_SCOPE_AGENT);
      int target = NSL * (t + 1);
      int guard = 0;
      while (__hip_atomic_load(&cnt[g], __ATOMIC_ACQUIRE, __HIP_MEMORY_SCOPE_AGENT) < target &&
             ++guard < (1 << 18)) {
        __builtin_amdgcn_s_sleep(1);
      }
    }
    __syncthreads();

    // ---- gather all 8 chunks -> LDS B-frag h region; stage/prefetch x ----
    {
      const unsigned int* __restrict__ src = &HbufU[((size_t)(t & 1) * NGRP + g) * 2048];
      int j = tid;                               // unit 0..255
      int kt = 4 + (j >> 5);
      int dbase = kt * 512 + ((j & 31) >> 3) * 128 + (j & 7);
#pragma unroll
      for (int cc = 0; cc < 8; ++cc) {
        unsigned int v = __hip_atomic_load(&src[j * 8 + cc], __ATOMIC_RELAXED,
                                           __HIP_MEMORY_SCOPE_AGENT);
        xh[dbase + (2 * cc) * 8] = (unsigned short)(v & 0xffffu);
        xh[dbase + (2 * cc + 1) * 8] = (unsigned short)(v >> 16);
      }
      if (t + 1 < lmax) {
        bf16x8 xv;
        xv[0] = (short)f32_to_bf16(xpa.x); xv[1] = (short)f32_to_bf16(xpa.y);
        xv[2] = (short)f32_to_bf16(xpa.z); xv[3] = (short)f32_to_bf16(xpa.w);
        xv[4] = (short)f32_to_bf16(xpb.x); xv[5] = (short)f32_to_bf16(xpb.y);
        xv[6] = (short)f32_to_bf16(xpb.z); xv[7] = (short)f32_to_bf16(xpb.w);
        *(bf16x8*)&xh[xdst] = xv;
        if (t + 2 < lmax) {
          xpa = *(const float4*)(xptr + (size_t)(t + 2) * NI);
          xpb = *(const float4*)(xptr + (size_t)(t + 2) * NI + 4);
        }
      }
    }
    __syncthreads();
  }

  // ---- publish final f32 h chunk ----
  if (lane < 32) {
#pragma unroll
    for (int r = 0; r < 4; ++r) hf[(8 * w + 4 * quad + r) * 16 + col] = h[r];
  }
  __syncthreads();
  {
    const unsigned int* hfu = (const unsigned int*)hf;
    __hip_atomic_store(&HfinU[(size_t)g * 4096 + m * 512 + 2 * tid], hfu[2 * tid],
                       __ATOMIC_RELAXED, __HIP_MEMORY_SCOPE_AGENT);
    __hip_atomic_store(&HfinU[(size_t)g * 4096 + m * 512 + 2 * tid + 1], hfu[2 * tid + 1],
                       __ATOMIC_RELAXED, __HIP_MEMORY_SCOPE_AGENT);
  }
  __threadfence();
  __syncthreads();
  if (tid == 0) {
    __hip_atomic_fetch_add(&cnt[g], 1, __ATOMIC_RELEASE, __HIP_MEMORY_SCOPE_AGENT);
    int target = NSL * (lmax + 1);
    int guard = 0;
    while (__hip_atomic_load(&cnt[g], __ATOMIC_ACQUIRE, __HIP_MEMORY_SCOPE_AGENT) < target &&
           ++guard < (1 << 18)) {
      __builtin_amdgcn_s_sleep(1);
    }
  }
  __syncthreads();

  // ---- LayerNorm: slice m normalizes seqs 2m, 2m+1; thread tid = unit ----
  {
    float v0 = __uint_as_float(__hip_atomic_load(&HfinU[(size_t)g * 4096 + tid * 16 + 2 * m],
                                                 __ATOMIC_RELAXED, __HIP_MEMORY_SCOPE_AGENT));
    float v1 = __uint_as_float(__hip_atomic_load(&HfinU[(size_t)g * 4096 + tid * 16 + 2 * m + 1],
                                                 __ATOMIC_RELAXED, __HIP_MEMORY_SCOPE_AGENT));
    float s0 = v0, q0 = v0 * v0, s1 = v1, q1 = v1 * v1;
#pragma unroll
    for (int off = 32; off > 0; off >>= 1) {
      s0 += __shfl_xor(s0, off);
      q0 += __shfl_xor(q0, off);
      s1 += __shfl_xor(s1, off);
      q1 += __shfl_xor(q1, off);
    }
    if (lane == 0) {
      red[w] = s0; red[4 + w] = q0; red[8 + w] = s1; red[12 + w] = q1;
    }
    __syncthreads();
    if (tid == 0) {
      float S0 = red[0] + red[1] + red[2] + red[3];
      float Q0 = red[4] + red[5] + red[6] + red[7];
      float S1 = red[8] + red[9] + red[10] + red[11];
      float Q1 = red[12] + red[13] + red[14] + red[15];
      float mu0 = S0 * (1.f / NH), mu1 = S1 * (1.f / NH);
      red[16] = mu0;
      red[17] = rsqrtf(Q0 * (1.f / NH) - mu0 * mu0 + EPSV);
      red[18] = mu1;
      red[19] = rsqrtf(Q1 * (1.f / NH) - mu1 * mu1 + EPSV);
    }
    __syncthreads();
    float gm = gamma[tid], bt = beta[tid];
    out[(size_t)sseq[2 * m] * NH + tid]     = (v0 - red[16]) * red[17] * gm + bt;
    out[(size_t)sseq[2 * m + 1] * NH + tid] = (v1 - red[18]) * red[19] * gm + bt;
  }
}

extern "C" void kernel_launch(void* const* d_in, const int* in_sizes, int n_in,
                              void* d_out, int out_size, void* d_ws, size_t ws_size,
                              hipStream_t stream) {
  const float* X       = (const float*)d_in[0];
  const int*   lengths = (const int*)d_in[1];
  const float* W_ih    = (const float*)d_in[2];
  const float* W_hh    = (const float*)d_in[3];
  const float* b_ih    = (const float*)d_in[4];
  const float* b_hh    = (const float*)d_in[5];
  const float* gamma   = (const float*)d_in[6];
  const float* beta    = (const float*)d_in[7];
  float* out = (float*)d_out;

  // workspace layout:
  //   Wsw   768 KB  (bf16 A-frag swizzled weights)
  //   bsum    4 KB
  //   perm    2 KB
  //   cnt   128 B   (32 group counters)
  //   HbufU 512 KB  (2 x 32 x 2048 uints, bf16 h exchange, double-buffered)
  //   HfinU 512 KB  (32 x 4096 uints, f32 final h)
  char* p = (char*)d_ws;
  unsigned short* Wsw = (unsigned short*)p;            p += (size_t)64 * NKT * 512 * 8 * 2;
  float* bsum = (float*)p;                             p += NG * sizeof(float);
  int* perm = (int*)p;                                 p += NB * sizeof(int);
  int* cnt = (int*)p;                                  p += 128;
  unsigned int* HbufU = (unsigned int*)p;              p += (size_t)2 * NGRP * 2048 * 4;
  unsigned int* HfinU = (unsigned int*)p;

  int total = 64 * NKT * 512 * 8;
  prep_kernel<<<(total + 255) / 256, 256, 0, stream>>>(W_ih, W_hh, b_ih, b_hh, Wsw, bsum, cnt);
  sort_kernel<<<1, NB, 0, stream>>>(lengths, perm);
  lstm_ln_kernel<<<NGRP * NSL, 256, 0, stream>>>(X, lengths, perm, Wsw, bsum, gamma, beta,
                                                 out, HbufU, HfinU, cnt);
}

// Round 6
// 7002.102 us; speedup vs baseline: 1.2746x; 1.2746x over previous
//
#include <hip/hip_runtime.h>

// Problem constants
#define NB 512   // batch
#define NT 512   // time
#define NI 128   // input dim
#define NH 256   // hidden dim
#define NG 1024  // 4*NH gate rows
#define NKT 12   // K tiles of 32 (K = 384 = [x(128) | h(256)])
#define GS 16    // sequences per group (= MFMA N)
#define NGRP 32  // groups
#define EPSV 1e-5f

typedef __attribute__((ext_vector_type(8))) short bf16x8;
typedef __attribute__((ext_vector_type(4))) float f32x4;

__device__ __forceinline__ unsigned short f32_to_bf16(float f) {
  unsigned int u = __float_as_uint(f);
  u += 0x7fffu + ((u >> 16) & 1u);   // RNE
  return (unsigned short)(u >> 16);
}
__device__ __forceinline__ float sigm(float x) { return 1.f / (1.f + __expf(-x)); }
__device__ __forceinline__ float tanhv(float x) { return 1.f - 2.f / (1.f + __expf(2.f * x)); }

// ---------------------------------------------------------------------------
// Prep: swizzle fused weights into A-fragment order.
// Frag id F = (w*8 + i)*12 + kt, w=wave 0..7, i=row-tile-slot 0..7, kt=k-tile.
// Row-tile rt = 8*i + w; gate-row grow = 16*rt + (lane&15);
// k = kt*32 + (lane>>4)*8 + elem.  Linear: (F*64 + lane)*8 + elem.
// A wave's global_load_dwordx4 at frag F IS its mfma A-fragment (1 KB contig).
// ---------------------------------------------------------------------------
__global__ void prep_kernel(const float* __restrict__ W_ih, const float* __restrict__ W_hh,
                            const float* __restrict__ b_ih, const float* __restrict__ b_hh,
                            unsigned short* __restrict__ Wsw, float* __restrict__ bsum) {
  int idx = blockIdx.x * blockDim.x + threadIdx.x;   // 768*64*8 = 393216
  if (idx < 768 * 512) {
    int e    = idx & 7;
    int lane = (idx >> 3) & 63;
    int F    = idx >> 9;            // 0..767
    int kt   = F % NKT;
    int t2   = F / NKT;             // w*8 + i
    int i    = t2 & 7;
    int w    = t2 >> 3;
    int rt   = 8 * i + w;
    int grow = 16 * rt + (lane & 15);
    int k    = kt * 32 + (lane >> 4) * 8 + e;
    float v = (k < NI) ? W_ih[grow * NI + k] : W_hh[grow * NH + (k - NI)];
    Wsw[idx] = f32_to_bf16(v);
  }
  if (idx < NG) bsum[idx] = b_ih[idx] + b_hh[idx];
}

// ---------------------------------------------------------------------------
// Rank-sort by length (descending) -> perm
// ---------------------------------------------------------------------------
__global__ void sort_kernel(const int* __restrict__ lengths, int* __restrict__ perm) {
  int i = threadIdx.x;
  __shared__ int L[NB];
  int li = lengths[i];
  L[i] = li;
  __syncthreads();
  int r = 0;
  for (int k = 0; k < NB; ++k) {
    int lk = L[k];
    r += (lk > li) || (lk == li && k < i);
  }
  perm[r] = i;
}

// ---------------------------------------------------------------------------
// Main: 32 blocks x 512 threads (8 waves, 2/SIMD, 256-VGPR cap).
// Block = 16 sorted sequences, fully independent (no cross-CU traffic).
// Wave w owns row-tiles rt=8i+w, i=0..7: all 4 gates of unit blocks
// [16w,16w+16) (even i) and [128+16w,+16) (odd i) -> lane-local cell update.
// Weight residency: i=0,1 + i=2(kt<8) in VGPRs (32 frags = 128 regs);
// i=2(kt>=8) + i=3(kt<2) in LDS (6 frags/wave = 48 KB);
// rest (58 frags/wave = 464 KB/step) streamed from L2, 2-deep pipelined.
// ---------------------------------------------------------------------------
__global__ __launch_bounds__(512, 2)
void lstm_ln_kernel(const float* __restrict__ X, const int* __restrict__ lengths,
                    const int* __restrict__ perm, const unsigned short* __restrict__ Wsw,
                    const float* __restrict__ bsum, const float* __restrict__ gamma,
                    const float* __restrict__ beta, float* __restrict__ out) {
  __shared__ alignas(16) unsigned short wlds[48 * 512];  // 48 KB resident weights / hf reuse
  __shared__ alignas(16) unsigned short xh[NKT * 512];   // 12 KB B-frag [x | h]
  __shared__ alignas(16) float blds[1024];               // 4 KB bias frags

  const int g    = blockIdx.x;
  const int tid  = threadIdx.x;
  const int w    = tid >> 6;
  const int lane = tid & 63;
  const int quad = lane >> 4;
  const int col  = lane & 15;

  // bias fragments: blds[w'*128 + i*16 + q*4 + r] = bsum[16*(8i+w') + q*4 + r]
  for (int idx = tid; idx < 1024; idx += 512) {
    int w2 = idx >> 7, i2 = (idx >> 4) & 7, q2 = (idx >> 2) & 3, r2 = idx & 3;
    blds[idx] = bsum[16 * (8 * i2 + w2) + q2 * 4 + r2];
  }
  for (int v = tid; v < NKT * 512; v += 512) xh[v] = 0;   // h(0) = 0

  const int lmax = lengths[perm[g * GS]];          // sorted desc
  const int lenc = lengths[perm[g * GS + col]];    // my column's length

  const bf16x8* __restrict__ Aw = (const bf16x8*)Wsw + (size_t)w * 96 * 64 + lane;

  // ---- persistent VGPR frags: F=0..23 (i=0,1), F=24..31 (i=2, kt<8) ----
  bf16x8 Wp[32];
#pragma unroll
  for (int f = 0; f < 32; ++f) Wp[f] = Aw[f * 64];

  // ---- LDS frags: li 0..3 -> (i=2, kt=8+li) F=32+li; li 4,5 -> (i=3,kt) F=36+kt ----
#pragma unroll
  for (int li = 0; li < 6; ++li) {
    bf16x8 v = Aw[((li < 4) ? (32 + li) : (36 + (li - 4))) * 64];
    *(bf16x8*)&wlds[(w * 6 + li) * 512 + lane * 8] = v;
  }

  // ---- x staging: thread -> (seq, 4 consecutive k) ----
  const int xseq = tid >> 5;
  const int k0 = (tid & 31) * 4;
  const float* __restrict__ xptr =
      X + (size_t)perm[g * GS + xseq] * NT * NI + k0;
  const int offX = (k0 >> 5) * 512 + (((k0 & 31) >> 3) * 16 + xseq) * 8 + (k0 & 7);

  // stage x(0)
  {
    float4 a = *(const float4*)xptr;
    unsigned int p0 = (unsigned int)f32_to_bf16(a.x) | ((unsigned int)f32_to_bf16(a.y) << 16);
    unsigned int p1 = (unsigned int)f32_to_bf16(a.z) | ((unsigned int)f32_to_bf16(a.w) << 16);
    uint2 pk; pk.x = p0; pk.y = p1;
    *(uint2*)&xh[offX] = pk;
  }
  float4 xp;
  if (lmax > 1) xp = *(const float4*)(xptr + NI);   // prefetch x(1)

  // ---- h write-back offsets (block A: units 16w+quad*4+r; B: +128) ----
  const int kA = 128 + 16 * w + quad * 4;
  const int kB = 256 + 16 * w + quad * 4;
  const int offA = (kA >> 5) * 512 + ((((kA & 31) >> 3) * 16) + col) * 8 + (kA & 7);
  const int offB = (kB >> 5) * 512 + ((((kB & 31) >> 3) * 16) + col) * 8 + (kB & 7);

  float cA[4] = {0.f, 0.f, 0.f, 0.f}, hA[4] = {0.f, 0.f, 0.f, 0.f};
  float cB[4] = {0.f, 0.f, 0.f, 0.f}, hB[4] = {0.f, 0.f, 0.f, 0.f};

  // streamed frag ids: i=4..7 -> F=48+kt,60+kt,72+kt,84+kt ; i=3 (kt>=2) -> F=36+kt
#define ISSUE(ktc, S)                                   \
  do {                                                  \
    S[0] = Aw[(48 + (ktc)) * 64];                       \
    S[1] = Aw[(60 + (ktc)) * 64];                       \
    S[2] = Aw[(72 + (ktc)) * 64];                       \
    S[3] = Aw[(84 + (ktc)) * 64];                       \
    if ((ktc) >= 2) S[4] = Aw[(36 + (ktc)) * 64];       \
  } while (0)

  for (int t = 0; t < lmax; ++t) {
    __syncthreads();   // xh complete: x(t) + h(t-1)

    bf16x8 s0[5], s1[5];
    ISSUE(0, s0);
    ISSUE(1, s1);

    f32x4 acc[8];
#pragma unroll
    for (int i = 0; i < 8; ++i)
      acc[i] = *(const f32x4*)&blds[w * 128 + i * 16 + quad * 4];

#pragma unroll
    for (int kt = 0; kt < NKT; ++kt) {
      bf16x8 bf = *(const bf16x8*)&xh[kt * 512 + lane * 8];
      bf16x8* S = (kt & 1) ? s1 : s0;
      acc[0] = __builtin_amdgcn_mfma_f32_16x16x32_bf16(Wp[kt], bf, acc[0], 0, 0, 0);
      acc[1] = __builtin_amdgcn_mfma_f32_16x16x32_bf16(Wp[12 + kt], bf, acc[1], 0, 0, 0);
      bf16x8 a2;
      if (kt < 8) a2 = Wp[24 + kt];
      else        a2 = *(const bf16x8*)&wlds[(w * 6 + (kt - 8)) * 512 + lane * 8];
      acc[2] = __builtin_amdgcn_mfma_f32_16x16x32_bf16(a2, bf, acc[2], 0, 0, 0);
      bf16x8 a3;
      if (kt < 2) a3 = *(const bf16x8*)&wlds[(w * 6 + 4 + kt) * 512 + lane * 8];
      else        a3 = S[4];
      acc[3] = __builtin_amdgcn_mfma_f32_16x16x32_bf16(a3, bf, acc[3], 0, 0, 0);
      acc[4] = __builtin_amdgcn_mfma_f32_16x16x32_bf16(S[0], bf, acc[4], 0, 0, 0);
      acc[5] = __builtin_amdgcn_mfma_f32_16x16x32_bf16(S[1], bf, acc[5], 0, 0, 0);
      acc[6] = __builtin_amdgcn_mfma_f32_16x16x32_bf16(S[2], bf, acc[6], 0, 0, 0);
      acc[7] = __builtin_amdgcn_mfma_f32_16x16x32_bf16(S[3], bf, acc[7], 0, 0, 0);
      if (kt + 2 < NKT) ISSUE(kt + 2, S);
    }

    // ---- lane-local cell update (gate order [i,f,g,o]) ----
    const bool upd = (t < lenc);
#pragma unroll
    for (int r = 0; r < 4; ++r) {
      float ig = sigm(acc[0][r]);
      float fg = sigm(acc[2][r]);
      float gg = tanhv(acc[4][r]);
      float og = sigm(acc[6][r]);
      float cn = fg * cA[r] + ig * gg;
      float hn = og * tanhv(cn);
      if (upd) { cA[r] = cn; hA[r] = hn; }
      ig = sigm(acc[1][r]);
      fg = sigm(acc[3][r]);
      gg = tanhv(acc[5][r]);
      og = sigm(acc[7][r]);
      cn = fg * cB[r] + ig * gg;
      hn = og * tanhv(cn);
      if (upd) { cB[r] = cn; hB[r] = hn; }
    }

    __syncthreads();   // all B-frag reads done before overwrite

    {  // write h(t) (frozen lanes rewrite old value)
      uint2 pa, pb;
      pa.x = (unsigned int)f32_to_bf16(hA[0]) | ((unsigned int)f32_to_bf16(hA[1]) << 16);
      pa.y = (unsigned int)f32_to_bf16(hA[2]) | ((unsigned int)f32_to_bf16(hA[3]) << 16);
      pb.x = (unsigned int)f32_to_bf16(hB[0]) | ((unsigned int)f32_to_bf16(hB[1]) << 16);
      pb.y = (unsigned int)f32_to_bf16(hB[2]) | ((unsigned int)f32_to_bf16(hB[3]) << 16);
      *(uint2*)&xh[offA] = pa;
      *(uint2*)&xh[offB] = pb;
    }
    if (t + 1 < lmax) {   // stage x(t+1), prefetch x(t+2)
      unsigned int p0 = (unsigned int)f32_to_bf16(xp.x) | ((unsigned int)f32_to_bf16(xp.y) << 16);
      unsigned int p1 = (unsigned int)f32_to_bf16(xp.z) | ((unsigned int)f32_to_bf16(xp.w) << 16);
      uint2 pk; pk.x = p0; pk.y = p1;
      *(uint2*)&xh[offX] = pk;
      if (t + 2 < lmax) xp = *(const float4*)(xptr + (size_t)(t + 2) * NI);
    }
  }
#undef ISSUE

  // ---- LayerNorm: reuse wlds as f32 hf[seq][unit] ----
  __syncthreads();
  float* hf = (float*)wlds;
  {
    int jA = 16 * w + quad * 4;
#pragma unroll
    for (int r = 0; r < 4; ++r) {
      hf[col * 256 + jA + r] = hA[r];
      hf[col * 256 + 128 + jA + r] = hB[r];
    }
  }
  __syncthreads();

  // wave w normalizes sequences 2w and 2w+1
  float4 v0 = *(const float4*)&hf[(2 * w) * 256 + lane * 4];
  float4 v1 = *(const float4*)&hf[(2 * w + 1) * 256 + lane * 4];
  float s0 = v0.x + v0.y + v0.z + v0.w;
  float q0 = v0.x * v0.x + v0.y * v0.y + v0.z * v0.z + v0.w * v0.w;
  float s1 = v1.x + v1.y + v1.z + v1.w;
  float q1 = v1.x * v1.x + v1.y * v1.y + v1.z * v1.z + v1.w * v1.w;
#pragma unroll
  for (int off = 32; off > 0; off >>= 1) {
    s0 += __shfl_xor(s0, off);
    q0 += __shfl_xor(q0, off);
    s1 += __shfl_xor(s1, off);
    q1 += __shfl_xor(q1, off);
  }
  float mu0 = s0 * (1.f / NH), mu1 = s1 * (1.f / NH);
  float rs0 = rsqrtf(q0 * (1.f / NH) - mu0 * mu0 + EPSV);
  float rs1 = rsqrtf(q1 * (1.f / NH) - mu1 * mu1 + EPSV);
  float4 g4 = *(const float4*)(gamma + lane * 4);
  float4 b4 = *(const float4*)(beta + lane * 4);
  int sb0 = perm[g * GS + 2 * w];
  int sb1 = perm[g * GS + 2 * w + 1];
  float4 o0, o1;
  o0.x = (v0.x - mu0) * rs0 * g4.x + b4.x;
  o0.y = (v0.y - mu0) * rs0 * g4.y + b4.y;
  o0.z = (v0.z - mu0) * rs0 * g4.z + b4.z;
  o0.w = (v0.w - mu0) * rs0 * g4.w + b4.w;
  o1.x = (v1.x - mu1) * rs1 * g4.x + b4.x;
  o1.y = (v1.y - mu1) * rs1 * g4.y + b4.y;
  o1.z = (v1.z - mu1) * rs1 * g4.z + b4.z;
  o1.w = (v1.w - mu1) * rs1 * g4.w + b4.w;
  *(float4*)(out + (size_t)sb0 * NH + lane * 4) = o0;
  *(float4*)(out + (size_t)sb1 * NH + lane * 4) = o1;
}

extern "C" void kernel_launch(void* const* d_in, const int* in_sizes, int n_in,
                              void* d_out, int out_size, void* d_ws, size_t ws_size,
                              hipStream_t stream) {
  const float* X       = (const float*)d_in[0];
  const int*   lengths = (const int*)d_in[1];
  const float* W_ih    = (const float*)d_in[2];
  const float* W_hh    = (const float*)d_in[3];
  const float* b_ih    = (const float*)d_in[4];
  const float* b_hh    = (const float*)d_in[5];
  const float* gamma   = (const float*)d_in[6];
  const float* beta    = (const float*)d_in[7];
  float* out = (float*)d_out;

  // workspace: Wsw 768 KB | bsum 4 KB | perm 2 KB
  unsigned short* Wsw = (unsigned short*)d_ws;
  float* bsum = (float*)((char*)d_ws + (size_t)768 * 512 * sizeof(unsigned short));
  int* perm = (int*)((char*)bsum + NG * sizeof(float));

  int total = 768 * 512;
  prep_kernel<<<(total + 255) / 256, 256, 0, stream>>>(W_ih, W_hh, b_ih, b_hh, Wsw, bsum);
  sort_kernel<<<1, NB, 0, stream>>>(lengths, perm);
  lstm_ln_kernel<<<NGRP, 512, 0, stream>>>(X, lengths, perm, Wsw, bsum, gamma, beta, out);
}